// Round 1
// baseline (412.332 us; speedup 1.0000x reference)
//
#include <hip/hip_runtime.h>
#include <hip/hip_bf16.h>

// Problem constants (from reference setup_inputs)
#define BATCH 32
#define SEQ   1024
#define DCH   256      // channels
#define TMAX  4096
#define MROWS (BATCH * SEQ)   // 32768
#define EPS   1e-5f

// ---------------------------------------------------------------------------
// Fused conv1d(K=3, pad=1) + bias + LayerNorm + ReLU  (optionally + linear head)
// GEMM view: C[m][n] = sum_{k,c} Xpad[m+k-1][c] * W[k*256+c][n]
// Block: 64 rows (one batch-aligned stripe) x all 256 cols; 256 threads.
// Thread (tx,ty): rows m0+ty*4..+3, cols {r*64 + tx*4 + j}, acc[4][16].
// ---------------------------------------------------------------------------
template <bool FUSE_OUT>
__global__ __launch_bounds__(256) void conv_ln_kernel(
    const float* __restrict__ X,     // [MROWS][256]
    const float* __restrict__ W,     // [768][256]  (K,in,out flattened)
    const float* __restrict__ bias,  // [256]
    const float* __restrict__ gam,   // [256]
    const float* __restrict__ bet,   // [256]
    const float* __restrict__ mask,  // [MROWS]
    const float* __restrict__ Wl,    // [256] (FUSE_OUT only)
    const float* __restrict__ bl,    // [1]   (FUSE_OUT only)
    float* __restrict__ Y)           // [MROWS][256] or dur_pred [MROWS]
{
    __shared__ float Xst[16][68];    // [cc][i], i=0..65 -> rows m0-1..m0+64
    __shared__ float Bs[48][256];    // [k*16+cc][n]

    const int tid = threadIdx.x;
    const int tx  = tid & 15;
    const int ty  = tid >> 4;
    const int tx4 = tx * 4;
    const int m0  = blockIdx.x * 64;
    const int batch_lo = (m0 >> 10) << 10;
    const int batch_hi = batch_lo + SEQ;

    float acc[4][16];
    // init with bias (conv bias folded into accumulator)
    {
        #pragma unroll
        for (int r = 0; r < 4; ++r) {
            float4 bv = *reinterpret_cast<const float4*>(bias + r * 64 + tx4);
            #pragma unroll
            for (int mr = 0; mr < 4; ++mr) {
                acc[mr][r * 4 + 0] = bv.x;
                acc[mr][r * 4 + 1] = bv.y;
                acc[mr][r * 4 + 2] = bv.z;
                acc[mr][r * 4 + 3] = bv.w;
            }
        }
    }

    for (int ch = 0; ch < 16; ++ch) {
        const int c0 = ch * 16;
        __syncthreads();   // protect LDS from previous iteration's readers
        // ---- stage X tile (transposed, with halo + batch-edge zero pad) ----
        {
            const int cc = tid & 15;
            const int i0 = tid >> 4;
            #pragma unroll
            for (int i = i0; i < 66; i += 16) {
                const int gm = m0 - 1 + i;
                float v = 0.f;
                if (gm >= batch_lo && gm < batch_hi) {
                    v = X[gm * 256 + c0 + cc];
                    if (!FUSE_OUT) v *= mask[gm];   // layer-1 input masking
                }
                Xst[cc][i] = v;
            }
        }
        // ---- stage W tile: rows k*256 + c0 + cc, k=0..2, cc=0..15 ----
        #pragma unroll
        for (int rep = 0; rep < 12; ++rep) {
            const int f    = rep * 256 + tid;   // float4 index, 0..3071
            const int row  = f >> 6;            // 0..47
            const int col4 = f & 63;
            const int wrow = (row >> 4) * 256 + c0 + (row & 15);
            const float4 wv = *reinterpret_cast<const float4*>(W + wrow * 256 + col4 * 4);
            *reinterpret_cast<float4*>(&Bs[row][col4 * 4]) = wv;
        }
        __syncthreads();
        // ---- compute ----
        #pragma unroll 4
        for (int cc = 0; cc < 16; ++cc) {
            float a[6];
            {
                const float4 a03 = *reinterpret_cast<const float4*>(&Xst[cc][ty * 4]);
                const float2 a45 = *reinterpret_cast<const float2*>(&Xst[cc][ty * 4 + 4]);
                a[0] = a03.x; a[1] = a03.y; a[2] = a03.z; a[3] = a03.w;
                a[4] = a45.x; a[5] = a45.y;
            }
            #pragma unroll
            for (int k = 0; k < 3; ++k) {
                const int kk = k * 16 + cc;
                #pragma unroll
                for (int r = 0; r < 4; ++r) {
                    const float4 bf = *reinterpret_cast<const float4*>(&Bs[kk][r * 64 + tx4]);
                    #pragma unroll
                    for (int mr = 0; mr < 4; ++mr) {
                        const float av = a[mr + k];
                        acc[mr][r * 4 + 0] += av * bf.x;
                        acc[mr][r * 4 + 1] += av * bf.y;
                        acc[mr][r * 4 + 2] += av * bf.z;
                        acc[mr][r * 4 + 3] += av * bf.w;
                    }
                }
            }
        }
    }

    // ---- epilogue: LayerNorm (+ReLU), optionally fused linear head ----
    float gg[16], bb[16], wl[16];
    #pragma unroll
    for (int r = 0; r < 4; ++r) {
        const float4 gv = *reinterpret_cast<const float4*>(gam + r * 64 + tx4);
        const float4 bv = *reinterpret_cast<const float4*>(bet + r * 64 + tx4);
        gg[r*4+0]=gv.x; gg[r*4+1]=gv.y; gg[r*4+2]=gv.z; gg[r*4+3]=gv.w;
        bb[r*4+0]=bv.x; bb[r*4+1]=bv.y; bb[r*4+2]=bv.z; bb[r*4+3]=bv.w;
        if (FUSE_OUT) {
            const float4 wv = *reinterpret_cast<const float4*>(Wl + r * 64 + tx4);
            wl[r*4+0]=wv.x; wl[r*4+1]=wv.y; wl[r*4+2]=wv.z; wl[r*4+3]=wv.w;
        }
    }

    #pragma unroll
    for (int mr = 0; mr < 4; ++mr) {
        float s = 0.f, sq = 0.f;
        #pragma unroll
        for (int q = 0; q < 16; ++q) { s += acc[mr][q]; sq += acc[mr][q] * acc[mr][q]; }
        #pragma unroll
        for (int off = 1; off < 16; off <<= 1) {
            s  += __shfl_xor(s,  off, 64);
            sq += __shfl_xor(sq, off, 64);
        }
        const float mean = s * (1.f / 256.f);
        const float var  = sq * (1.f / 256.f) - mean * mean;
        const float rstd = rsqrtf(var + EPS);
        const int gm = m0 + ty * 4 + mr;
        if (!FUSE_OUT) {
            #pragma unroll
            for (int r = 0; r < 4; ++r) {
                float4 o;
                float v0 = (acc[mr][r*4+0] - mean) * rstd * gg[r*4+0] + bb[r*4+0];
                float v1 = (acc[mr][r*4+1] - mean) * rstd * gg[r*4+1] + bb[r*4+1];
                float v2 = (acc[mr][r*4+2] - mean) * rstd * gg[r*4+2] + bb[r*4+2];
                float v3 = (acc[mr][r*4+3] - mean) * rstd * gg[r*4+3] + bb[r*4+3];
                o.x = fmaxf(v0, 0.f); o.y = fmaxf(v1, 0.f);
                o.z = fmaxf(v2, 0.f); o.w = fmaxf(v3, 0.f);
                *reinterpret_cast<float4*>(Y + gm * 256 + r * 64 + tx4) = o;
            }
        } else {
            float d = 0.f;
            #pragma unroll
            for (int q = 0; q < 16; ++q) {
                float v = (acc[mr][q] - mean) * rstd * gg[q] + bb[q];
                v = fmaxf(v, 0.f);
                d += v * wl[q];
            }
            #pragma unroll
            for (int off = 1; off < 16; off <<= 1) d += __shfl_xor(d, off, 64);
            if (tx == 0) {
                const float dd = (d + bl[0]) * mask[gm];
                Y[gm] = fmaxf(dd, 0.f);
            }
        }
    }
}

// ---------------------------------------------------------------------------
// Per-batch inclusive cumsum of reps = target + 1 (alpha == 1.0 exactly)
// ---------------------------------------------------------------------------
__global__ __launch_bounds__(256) void cumsum_kernel(
    const int* __restrict__ target, int* __restrict__ cum)
{
    const int b   = blockIdx.x;
    const int tid = threadIdx.x;
    const int base = b * SEQ + tid * 4;

    int vals[4];
    int s = 0;
    #pragma unroll
    for (int j = 0; j < 4; ++j) {
        s += target[base + j] + 1;
        vals[j] = s;
    }
    // wave-level inclusive scan of per-thread totals
    const int lane = tid & 63;
    int tot = s;
    #pragma unroll
    for (int off = 1; off < 64; off <<= 1) {
        int t = __shfl_up(tot, off, 64);
        if (lane >= off) tot += t;
    }
    __shared__ int wsum[4];
    const int wid = tid >> 6;
    if (lane == 63) wsum[wid] = tot;
    __syncthreads();
    int woff = 0;
    for (int w = 0; w < wid; ++w) woff += wsum[w];
    const int thr_excl = tot - s + woff;
    #pragma unroll
    for (int j = 0; j < 4; ++j) cum[base + j] = thr_excl + vals[j];
}

// ---------------------------------------------------------------------------
// Length regulation: binary search + gather, plus decoder_pos
// Block: 16 output frames x 256 channels; 256 threads (float4 copies).
// ---------------------------------------------------------------------------
__global__ __launch_bounds__(256) void regulate_kernel(
    const float* __restrict__ enc,   // [BATCH][SEQ][256]
    const int*  __restrict__ cum,    // [BATCH][SEQ]
    float* __restrict__ out,         // [BATCH][TMAX][256]
    float* __restrict__ pos)         // [BATCH][TMAX] (as float)
{
    const int b   = blockIdx.y;
    const int t0  = blockIdx.x * 16;
    const int tid = threadIdx.x;
    __shared__ int sidx[16];
    __shared__ int svalid[16];

    const int* c = cum + b * SEQ;
    if (tid < 16) {
        const int t = t0 + tid;
        const int total = c[SEQ - 1];
        int lo = 0, hi = SEQ;
        while (lo < hi) {
            const int mid = (lo + hi) >> 1;
            if (c[mid] <= t) lo = mid + 1; else hi = mid;
        }
        const int valid = (t < total) ? 1 : 0;
        sidx[tid]   = lo < (SEQ - 1) ? lo : (SEQ - 1);
        svalid[tid] = valid;
        pos[b * TMAX + t] = valid ? (float)(t + 1) : 0.f;
    }
    __syncthreads();

    const int r4  = tid >> 6;          // 0..3
    const int col = (tid & 63) * 4;
    #pragma unroll
    for (int g = 0; g < 4; ++g) {
        const int tt = g * 4 + r4;
        float4 v = make_float4(0.f, 0.f, 0.f, 0.f);
        if (svalid[tt])
            v = *reinterpret_cast<const float4*>(enc + (b * SEQ + sidx[tt]) * 256 + col);
        *reinterpret_cast<float4*>(out + (b * TMAX + t0 + tt) * 256 + col) = v;
    }
}

// ---------------------------------------------------------------------------
extern "C" void kernel_launch(void* const* d_in, const int* in_sizes, int n_in,
                              void* d_out, int out_size, void* d_ws, size_t ws_size,
                              hipStream_t stream) {
    const float* enc   = (const float*)d_in[0];   // [32,1024,256]
    const float* mask  = (const float*)d_in[1];   // [32,1024,1]
    const int*   target= (const int*)  d_in[2];   // [32,1024]
    // d_in[3] = mel_max_length (4096, hardcoded)
    const float* W1    = (const float*)d_in[4];
    const float* b1    = (const float*)d_in[5];
    const float* g1    = (const float*)d_in[6];
    const float* beta1 = (const float*)d_in[7];
    const float* W2    = (const float*)d_in[8];
    const float* b2    = (const float*)d_in[9];
    const float* g2    = (const float*)d_in[10];
    const float* beta2 = (const float*)d_in[11];
    const float* Wl    = (const float*)d_in[12];  // [256,1]
    const float* bl    = (const float*)d_in[13];  // [1]

    float* outF = (float*)d_out;
    float* out_main = outF;                                      // 32*4096*256
    float* out_pos  = outF + (size_t)BATCH * TMAX * DCH;         // 32*4096
    float* out_dur  = out_pos + (size_t)BATCH * TMAX;            // 32*1024

    // workspace layout
    float* h1  = (float*)d_ws;                                   // 32768*256 f32
    int*   cum = (int*)((char*)d_ws + (size_t)MROWS * DCH * sizeof(float));

    // duration predictor
    conv_ln_kernel<false><<<MROWS / 64, 256, 0, stream>>>(
        enc, W1, b1, g1, beta1, mask, nullptr, nullptr, h1);
    conv_ln_kernel<true><<<MROWS / 64, 256, 0, stream>>>(
        h1, W2, b2, g2, beta2, mask, Wl, bl, out_dur);

    // length regulator
    cumsum_kernel<<<BATCH, 256, 0, stream>>>(target, cum);
    regulate_kernel<<<dim3(TMAX / 16, BATCH), 256, 0, stream>>>(
        enc, cum, out_main, out_pos);
}

// Round 2
// 93.594 us; speedup vs baseline: 4.4055x; 4.4055x over previous
//
#include <hip/hip_runtime.h>
#include <hip/hip_bf16.h>

#define BATCH 32
#define SEQ   1024
#define DCH   256
#define TMAX  4096
#define MROWS (BATCH * SEQ)
#define EPS   1e-5f

typedef __attribute__((ext_vector_type(8))) short s16x8;   // 8 bf16 in 4 VGPRs
typedef __attribute__((ext_vector_type(4))) float f32x4;

#define NSTEPS 24
#define WROW_B 80                       // 40 bf16 per col-row (32 used + pad)
#define WTILE_B (256 * WROW_B)          // 20480 B per K-step tile
#define XST_B  (66 * 512)               // 33792 B X tile (66 rows x 256 bf16)
#define LDS_TOTAL (XST_B + 2 * WTILE_B) // 74752 B

__device__ __forceinline__ short f2bf(float f) {
    union { float f; unsigned u; } x; x.f = f;
    unsigned r = x.u + 0x7fffu + ((x.u >> 16) & 1u);   // RNE
    return (short)(r >> 16);
}

__device__ __forceinline__ void gload16(const void* g, void* l) {
    __builtin_amdgcn_global_load_lds(
        (const __attribute__((address_space(1))) unsigned int*)g,
        (__attribute__((address_space(3))) unsigned int*)l, 16, 0, 0);
}

// ---------------------------------------------------------------------------
// Weight prep: W [3][256][256] f32 -> Wp [24][256 cols][40] bf16 (transposed,
// padded to 80B rows so B-frag ds_read_b128 spreads across banks).
// ---------------------------------------------------------------------------
__global__ __launch_bounds__(256) void wprep(const float* __restrict__ W1,
                                             const float* __restrict__ W2,
                                             short* __restrict__ Wp1,
                                             short* __restrict__ Wp2)
{
    const int b = blockIdx.x;                 // 0..47
    const int s = b % NSTEPS;
    const float* W = (b < NSTEPS) ? W1 : W2;
    short* out = (b < NSTEPS) ? Wp1 : Wp2;
    const int n  = threadIdx.x;               // output channel (col)
    const int ko = s >> 3;
    const int cb = (s & 7) * 32;
    short tmp[40];
    #pragma unroll
    for (int kk = 0; kk < 32; ++kk)
        tmp[kk] = f2bf(W[(size_t)(ko * 256 + cb + kk) * 256 + n]);
    #pragma unroll
    for (int kk = 32; kk < 40; ++kk) tmp[kk] = 0;
    short* dst = out + ((size_t)s * 256 + n) * 40;
    #pragma unroll
    for (int i = 0; i < 5; ++i)
        *(s16x8*)(dst + i * 8) = *(const s16x8*)(tmp + i * 8);
}

// ---------------------------------------------------------------------------
// Fused conv1d(K=3,pad=1,per-batch) + bias + LayerNorm + ReLU  (MFMA bf16)
// HEAD=false: Y = h1 (bf16 [MROWS][256]);  HEAD=true: Y = dur_pred (f32).
// Block: 64 rows x 256 cols, 4 waves split N, acc[4][4] 16x16x32 frags.
// ---------------------------------------------------------------------------
template <bool HEAD>
__global__ __launch_bounds__(256, 2) void conv_mfma(
    const void* __restrict__ Xsrc,      // f32 enc (HEAD=0) or bf16 h1 (HEAD=1)
    const float* __restrict__ mask,     // [MROWS]
    const short* __restrict__ Wp,       // prepped [24][256][40] bf16
    const float* __restrict__ bias,
    const float* __restrict__ gam,
    const float* __restrict__ bet,
    const float* __restrict__ Wl,       // [256] (HEAD only)
    const float* __restrict__ bl,       // [1]   (HEAD only)
    void* __restrict__ Y)
{
    __shared__ __align__(16) char lds[LDS_TOTAL];
    char* const Xst = lds;
    char* const W0  = lds + XST_B;

    const int tid  = threadIdx.x;
    const int lane = tid & 63;
    const int wv   = tid >> 6;          // wave 0..3 -> cols wv*64..+63
    const int cl   = lane & 15;
    const int q    = lane >> 4;
    const int m0   = blockIdx.x * 64;
    const int blo  = m0 & ~(SEQ - 1);
    const int bhi  = blo + SEQ;

    // ---- stage X tile: rows m0-1 .. m0+64 (halo), XOR-swizzled 16B chunks ----
    for (int t = tid; t < 66 * 32; t += 256) {
        const int r  = t >> 5;
        const int ch = t & 31;
        const int grow = m0 - 1 + r;
        s16x8 v = {0, 0, 0, 0, 0, 0, 0, 0};
        if (grow >= blo && grow < bhi) {
            if (!HEAD) {
                const float* xf = (const float*)Xsrc + (size_t)grow * DCH + ch * 8;
                const float4 f0 = *(const float4*)xf;
                const float4 f1 = *(const float4*)(xf + 4);
                const float mk = mask[grow];
                v[0] = f2bf(f0.x * mk); v[1] = f2bf(f0.y * mk);
                v[2] = f2bf(f0.z * mk); v[3] = f2bf(f0.w * mk);
                v[4] = f2bf(f1.x * mk); v[5] = f2bf(f1.y * mk);
                v[6] = f2bf(f1.z * mk); v[7] = f2bf(f1.w * mk);
            } else {
                v = *(const s16x8*)((const char*)Xsrc + (size_t)grow * 512 + ch * 16);
            }
        }
        *(s16x8*)(Xst + r * 512 + ((ch ^ (r & 7)) << 4)) = v;
    }

    // ---- stage W step 0 (global_load_lds, 16B, linear dest) ----
    {
        const char* src = (const char*)Wp + wv * 5120 + lane * 16;
        char* dst = W0 + wv * 5120;
        #pragma unroll
        for (int i = 0; i < 5; ++i)
            gload16(src + i * 1024, dst + i * 1024);
    }

    // ---- init acc with conv bias (per output col) ----
    f32x4 acc[4][4];
    #pragma unroll
    for (int nc = 0; nc < 4; ++nc) {
        const float b = bias[wv * 64 + nc * 16 + cl];
        #pragma unroll
        for (int mr = 0; mr < 4; ++mr) acc[mr][nc] = (f32x4){b, b, b, b};
    }

    __syncthreads();

    // ---- K loop: s = ko*8 + ci ; stage s+1 while computing s ----
    for (int s = 0; s < NSTEPS; ++s) {
        char* const wbuf = W0 + (s & 1) * WTILE_B;
        if (s + 1 < NSTEPS) {
            const char* src = (const char*)Wp + (size_t)(s + 1) * WTILE_B + wv * 5120 + lane * 16;
            char* dst = W0 + ((s + 1) & 1) * WTILE_B + wv * 5120;
            #pragma unroll
            for (int i = 0; i < 5; ++i)
                gload16(src + i * 1024, dst + i * 1024);
        }
        const int ko  = s >> 3;
        const int chb = (s & 7) * 4 + q;    // 16B chunk of channel window
        s16x8 a[4], bb[4];
        #pragma unroll
        for (int mr = 0; mr < 4; ++mr) {
            const int tr = mr * 16 + cl + ko;           // tile row (incl. halo)
            a[mr] = *(const s16x8*)(Xst + tr * 512 + ((chb ^ (tr & 7)) << 4));
        }
        #pragma unroll
        for (int nc = 0; nc < 4; ++nc) {
            const int col = wv * 64 + nc * 16 + cl;
            bb[nc] = *(const s16x8*)(wbuf + col * WROW_B + (q << 4));
        }
        #pragma unroll
        for (int mr = 0; mr < 4; ++mr)
            #pragma unroll
            for (int nc = 0; nc < 4; ++nc)
                acc[mr][nc] = __builtin_amdgcn_mfma_f32_16x16x32_bf16(
                    a[mr], bb[nc], acc[mr][nc], 0, 0, 0);
        __syncthreads();
    }

    // ---- LayerNorm stats: 16-lane shfl + cross-wave LDS reduction ----
    float* red   = (float*)(lds + XST_B);          // [64][4 waves][2]
    float* stats = (float*)(lds + XST_B + 2048);   // [64][2] mean,rstd
    #pragma unroll
    for (int mr = 0; mr < 4; ++mr) {
        #pragma unroll
        for (int rg = 0; rg < 4; ++rg) {
            float s1 = 0.f, s2 = 0.f;
            #pragma unroll
            for (int nc = 0; nc < 4; ++nc) {
                const float v = acc[mr][nc][rg];
                s1 += v; s2 += v * v;
            }
            #pragma unroll
            for (int m = 1; m < 16; m <<= 1) {
                s1 += __shfl_xor(s1, m, 64);
                s2 += __shfl_xor(s2, m, 64);
            }
            if (cl == 0) {
                const int r = mr * 16 + q * 4 + rg;
                red[(r * 4 + wv) * 2]     = s1;
                red[(r * 4 + wv) * 2 + 1] = s2;
            }
        }
    }
    __syncthreads();
    if (tid < 64) {
        const float s1 = red[tid*8] + red[tid*8+2] + red[tid*8+4] + red[tid*8+6];
        const float s2 = red[tid*8+1] + red[tid*8+3] + red[tid*8+5] + red[tid*8+7];
        const float mean = s1 * (1.f / 256.f);
        const float var  = s2 * (1.f / 256.f) - mean * mean;
        stats[tid * 2]     = mean;
        stats[tid * 2 + 1] = rsqrtf(var + EPS);
    }
    __syncthreads();

    if (!HEAD) {
        float gv[4], bv[4];
        #pragma unroll
        for (int nc = 0; nc < 4; ++nc) {
            const int col = wv * 64 + nc * 16 + cl;
            gv[nc] = gam[col]; bv[nc] = bet[col];
        }
        short* y = (short*)Y;
        #pragma unroll
        for (int mr = 0; mr < 4; ++mr) {
            #pragma unroll
            for (int rg = 0; rg < 4; ++rg) {
                const int r = mr * 16 + q * 4 + rg;
                const float2 ms = *(const float2*)(stats + r * 2);
                #pragma unroll
                for (int nc = 0; nc < 4; ++nc) {
                    const int col = wv * 64 + nc * 16 + cl;
                    float v = (acc[mr][nc][rg] - ms.x) * ms.y * gv[nc] + bv[nc];
                    y[(size_t)(m0 + r) * DCH + col] = f2bf(fmaxf(v, 0.f));
                }
            }
        }
    } else {
        float gv[4], bv[4], wl[4];
        #pragma unroll
        for (int nc = 0; nc < 4; ++nc) {
            const int col = wv * 64 + nc * 16 + cl;
            gv[nc] = gam[col]; bv[nc] = bet[col]; wl[nc] = Wl[col];
        }
        float* red2 = (float*)(lds + XST_B + 4096);   // [64][4]
        #pragma unroll
        for (int mr = 0; mr < 4; ++mr) {
            #pragma unroll
            for (int rg = 0; rg < 4; ++rg) {
                const int r = mr * 16 + q * 4 + rg;
                const float2 ms = *(const float2*)(stats + r * 2);
                float p = 0.f;
                #pragma unroll
                for (int nc = 0; nc < 4; ++nc) {
                    float v = (acc[mr][nc][rg] - ms.x) * ms.y * gv[nc] + bv[nc];
                    p += fmaxf(v, 0.f) * wl[nc];
                }
                #pragma unroll
                for (int m = 1; m < 16; m <<= 1) p += __shfl_xor(p, m, 64);
                if (cl == 0) red2[r * 4 + wv] = p;
            }
        }
        __syncthreads();
        if (tid < 64) {
            float d = red2[tid*4] + red2[tid*4+1] + red2[tid*4+2] + red2[tid*4+3] + bl[0];
            d *= mask[m0 + tid];
            ((float*)Y)[m0 + tid] = fmaxf(d, 0.f);
        }
    }
}

// ---------------------------------------------------------------------------
// Per-batch inclusive cumsum of reps = target + 1 (alpha == 1.0)
// ---------------------------------------------------------------------------
__global__ __launch_bounds__(256) void cumsum_kernel(
    const int* __restrict__ target, int* __restrict__ cum)
{
    const int b   = blockIdx.x;
    const int tid = threadIdx.x;
    const int base = b * SEQ + tid * 4;

    int vals[4];
    int s = 0;
    #pragma unroll
    for (int j = 0; j < 4; ++j) {
        s += target[base + j] + 1;
        vals[j] = s;
    }
    const int lane = tid & 63;
    int tot = s;
    #pragma unroll
    for (int off = 1; off < 64; off <<= 1) {
        int t = __shfl_up(tot, off, 64);
        if (lane >= off) tot += t;
    }
    __shared__ int wsum[4];
    const int wid = tid >> 6;
    if (lane == 63) wsum[wid] = tot;
    __syncthreads();
    int woff = 0;
    for (int w = 0; w < wid; ++w) woff += wsum[w];
    const int thr_excl = tot - s + woff;
    #pragma unroll
    for (int j = 0; j < 4; ++j) cum[base + j] = thr_excl + vals[j];
}

// ---------------------------------------------------------------------------
// Length regulation: binary search + gather + decoder_pos
// ---------------------------------------------------------------------------
__global__ __launch_bounds__(256) void regulate_kernel(
    const float* __restrict__ enc,   // [BATCH][SEQ][256]
    const int*  __restrict__ cum,    // [BATCH][SEQ]
    float* __restrict__ out,         // [BATCH][TMAX][256]
    float* __restrict__ pos)         // [BATCH][TMAX]
{
    const int b   = blockIdx.y;
    const int t0  = blockIdx.x * 16;
    const int tid = threadIdx.x;
    __shared__ int sidx[16];
    __shared__ int svalid[16];

    const int* c = cum + b * SEQ;
    if (tid < 16) {
        const int t = t0 + tid;
        const int total = c[SEQ - 1];
        int lo = 0, hi = SEQ;
        while (lo < hi) {
            const int mid = (lo + hi) >> 1;
            if (c[mid] <= t) lo = mid + 1; else hi = mid;
        }
        const int valid = (t < total) ? 1 : 0;
        sidx[tid]   = lo < (SEQ - 1) ? lo : (SEQ - 1);
        svalid[tid] = valid;
        pos[b * TMAX + t] = valid ? (float)(t + 1) : 0.f;
    }
    __syncthreads();

    const int r4  = tid >> 6;
    const int col = (tid & 63) * 4;
    #pragma unroll
    for (int g = 0; g < 4; ++g) {
        const int tt = g * 4 + r4;
        float4 v = make_float4(0.f, 0.f, 0.f, 0.f);
        if (svalid[tt])
            v = *reinterpret_cast<const float4*>(enc + (size_t)(b * SEQ + sidx[tt]) * 256 + col);
        *reinterpret_cast<float4*>(out + (size_t)(b * TMAX + t0 + tt) * 256 + col) = v;
    }
}

// ---------------------------------------------------------------------------
extern "C" void kernel_launch(void* const* d_in, const int* in_sizes, int n_in,
                              void* d_out, int out_size, void* d_ws, size_t ws_size,
                              hipStream_t stream) {
    const float* enc   = (const float*)d_in[0];
    const float* mask  = (const float*)d_in[1];
    const int*   target= (const int*)  d_in[2];
    const float* W1    = (const float*)d_in[4];
    const float* b1    = (const float*)d_in[5];
    const float* g1    = (const float*)d_in[6];
    const float* beta1 = (const float*)d_in[7];
    const float* W2    = (const float*)d_in[8];
    const float* b2    = (const float*)d_in[9];
    const float* g2    = (const float*)d_in[10];
    const float* beta2 = (const float*)d_in[11];
    const float* Wl    = (const float*)d_in[12];
    const float* bl    = (const float*)d_in[13];

    float* outF = (float*)d_out;
    float* out_main = outF;                               // 32*4096*256
    float* out_pos  = outF + (size_t)BATCH * TMAX * DCH;  // 32*4096
    float* out_dur  = out_pos + (size_t)BATCH * TMAX;     // 32*1024

    char* ws = (char*)d_ws;
    short* h1  = (short*)ws;                                   // 16 MB bf16
    short* Wp1 = (short*)(ws + (size_t)MROWS * DCH * 2);       // 480 KB
    short* Wp2 = (short*)(ws + (size_t)MROWS * DCH * 2 + NSTEPS * WTILE_B);
    int*   cum = (int*)  (ws + (size_t)MROWS * DCH * 2 + 2 * (size_t)NSTEPS * WTILE_B);

    wprep<<<48, 256, 0, stream>>>(W1, W2, Wp1, Wp2);
    cumsum_kernel<<<BATCH, 256, 0, stream>>>(target, cum);
    conv_mfma<false><<<MROWS / 64, 256, 0, stream>>>(
        enc, mask, Wp1, b1, g1, beta1, nullptr, nullptr, h1);
    conv_mfma<true><<<MROWS / 64, 256, 0, stream>>>(
        h1, mask, Wp2, b2, g2, beta2, Wl, bl, out_dur);
    regulate_kernel<<<dim3(TMAX / 16, BATCH), 256, 0, stream>>>(
        enc, cum, out_main, out_pos);
}